// Round 1
// baseline (425.438 us; speedup 1.0000x reference)
//
#include <hip/hip_runtime.h>
#include <math.h>

// PositionFeaturizer on MI355X — round 0: full fused pipeline, correctness-first.
// Pipeline: memset(den/wsum/wsp) -> prep_weights(bf16 casts, K-pad W_in to 544)
//   -> ln_kernel (both LNs in one pass; writes z_att bf16 + zcat[0:512] bf16 + zero pad)
//   -> gemm_nt<0>: qk[N,1024] = z_att @ [Wq;Wk]^T + [bq;bk]      (fp32 out)
//   -> edge_kernel: per-edge logits (no segment-max: logits bounded ~|8|, exp safe;
//        softmax shift-invariant) -> atomic den/wsum/wsp accumulation
//   -> feat_kernel: feat = wsp/den - (wsum/den)*pos -> zcat[512:536] bf16
//   -> gemm_nt<1>: h = gelu_tanh(zcat @ W_in^T + b_in)            (bf16 out)
//   -> gemm_nt<2>: out = x + h @ W_out^T + b_out                  (fp32 out)
// GEMM: 16x16x32 bf16 MFMA, 128x128 tile, 4 waves of 64x64, BK=32, LDS stride 40.

typedef unsigned short u16;
typedef __attribute__((ext_vector_type(8))) short bf16x8;   // 8 bf16 in 4 VGPRs
typedef __attribute__((ext_vector_type(4))) float f32x4;

constexpr int N_NODES = 16384;
constexpr int E_EDGES = 262144;
constexpr int D = 512;
constexpr int KIN = 544;    // 536 padded to multiple of 32

// workspace layout (bytes)
constexpr size_t OFF_ZATT = 0;                       // 16384*512*2  = 16,777,216
constexpr size_t OFF_ZCAT = 16777216;                // 16384*544*2  = 17,825,792
constexpr size_t OFF_WQK  = 34603008;                // 1024*512*2   = 1,048,576
constexpr size_t OFF_BQK  = 35651584;                // 1024*4       = 4,096
constexpr size_t OFF_WIN  = 35655680;                // 1024*544*2   = 1,114,112
constexpr size_t OFF_WOUT = 36769792;                // 512*1024*2   = 1,048,576
constexpr size_t OFF_QK   = 37818368;                // 16384*1024*4 = 67,108,864
constexpr size_t OFF_DEN  = 104927232;               // 16384*8*4    = 524,288
constexpr size_t OFF_WSUM = 105451520;               // 524,288
constexpr size_t OFF_WSP  = 105975808;               // 16384*8*3*4  = 1,572,864
constexpr size_t OFF_HBF  = 107548672;               // 16384*1024*2 = 33,554,432
// total 141,103,104 bytes

static __device__ __forceinline__ u16 f2bf(float f) {
  union { float f; unsigned int u; } v; v.f = f;
  unsigned int u = v.u;
  u = u + 0x7FFFu + ((u >> 16) & 1u);   // RNE
  return (u16)(u >> 16);
}

// ---------------------------------------------------------------- weights cast
__global__ __launch_bounds__(256) void prep_weights(
    const float* __restrict__ Wq, const float* __restrict__ Wk,
    const float* __restrict__ bq, const float* __restrict__ bk,
    const float* __restrict__ W_in, const float* __restrict__ W_out,
    u16* __restrict__ wqk, float* __restrict__ bqk,
    u16* __restrict__ win, u16* __restrict__ wout)
{
  const int gid = blockIdx.x * 256 + threadIdx.x;
  if (gid < 512 * 1024) {
    wqk[gid]  = f2bf(gid < 512 * 512 ? Wq[gid] : Wk[gid - 512 * 512]);
    wout[gid] = f2bf(W_out[gid]);
  }
  if (gid < 1024 * 544) {
    const int r = gid / 544, c = gid - r * 544;
    win[gid] = f2bf(c < 536 ? W_in[r * 536 + c] : 0.f);
  }
  if (gid < 1024) bqk[gid] = gid < 512 ? bq[gid] : bk[gid - 512];
}

// ---------------------------------------------------------------- dual layernorm
__global__ __launch_bounds__(256) void ln_kernel(
    const float* __restrict__ x,
    const float* __restrict__ g1, const float* __restrict__ b1,
    const float* __restrict__ g2, const float* __restrict__ b2,
    u16* __restrict__ zatt, u16* __restrict__ zcat)
{
  const int row = blockIdx.x;
  const int t = threadIdx.x;
  const float2 v = *(const float2*)(x + (size_t)row * D + t * 2);
  float s = v.x + v.y;
  float s2 = v.x * v.x + v.y * v.y;
#pragma unroll
  for (int m = 1; m < 64; m <<= 1) {
    s  += __shfl_xor(s, m, 64);
    s2 += __shfl_xor(s2, m, 64);
  }
  __shared__ float red[8];
  const int wv = t >> 6;
  if ((t & 63) == 0) { red[wv] = s; red[4 + wv] = s2; }
  __syncthreads();
  s  = red[0] + red[1] + red[2] + red[3];
  s2 = red[4] + red[5] + red[6] + red[7];
  const float mu = s * (1.f / D);
  const float var = s2 * (1.f / D) - mu * mu;
  const float rs = rsqrtf(var + 1e-5f);
  const int c0 = t * 2;
  const float n0 = (v.x - mu) * rs, n1 = (v.y - mu) * rs;
  zatt[(size_t)row * D + c0]       = f2bf(n0 * g1[c0] + b1[c0]);
  zatt[(size_t)row * D + c0 + 1]   = f2bf(n1 * g1[c0 + 1] + b1[c0 + 1]);
  zcat[(size_t)row * KIN + c0]     = f2bf(n0 * g2[c0] + b2[c0]);
  zcat[(size_t)row * KIN + c0 + 1] = f2bf(n1 * g2[c0 + 1] + b2[c0 + 1]);
  if (t < 32) zcat[(size_t)row * KIN + D + t] = 0;   // feat slot + K-pad zeroed
}

// ---------------------------------------------------------------- NT GEMM (bf16 MFMA)
// C[M,Nn] = A[M,K] @ B[Nn,K]^T + bias.  EPI: 0=f32 out; 1=gelu->bf16 out; 2=+resid f32 out.
template <int EPI>
__global__ __launch_bounds__(256) void gemm_nt(
    const u16* __restrict__ A, const u16* __restrict__ B,
    const float* __restrict__ bias, const float* __restrict__ resid,
    void* __restrict__ Cout, int M, int Nn, int K)
{
  constexpr int BM = 128, BN = 128, BK = 32, LDT = 40;  // pad 32->40: 16B-aligned rows, 2-way banks (free)
  __shared__ __align__(16) u16 As[BM * LDT];
  __shared__ __align__(16) u16 Bs[BN * LDT];
  const int tid = threadIdx.x;
  const int lane = tid & 63;
  const int wave = tid >> 6;
  const int m0 = blockIdx.y * BM;
  const int n0 = blockIdx.x * BN;
  const int wm = (wave >> 1) * 64;
  const int wn = (wave & 1) * 64;
  const int fr = lane & 15;   // fragment m/n index
  const int fq = lane >> 4;   // quad -> k-group / row-group

  f32x4 acc[4][4];
#pragma unroll
  for (int i = 0; i < 4; ++i)
#pragma unroll
    for (int j = 0; j < 4; ++j) acc[i][j] = 0.f;

  const int srow = tid >> 2;            // 0..63
  const int skg = (tid & 3) * 8;        // k offset within tile
  for (int k0 = 0; k0 < K; k0 += BK) {
    __syncthreads();
#pragma unroll
    for (int i = 0; i < 2; ++i) {
      const int row = srow + i * 64;
      *(int4*)(As + row * LDT + skg) = *(const int4*)(A + (size_t)(m0 + row) * K + k0 + skg);
      *(int4*)(Bs + row * LDT + skg) = *(const int4*)(B + (size_t)(n0 + row) * K + k0 + skg);
    }
    __syncthreads();
    bf16x8 af[4], bfr[4];
#pragma unroll
    for (int mi = 0; mi < 4; ++mi)
      af[mi] = *(const bf16x8*)(As + (wm + mi * 16 + fr) * LDT + fq * 8);
#pragma unroll
    for (int ni = 0; ni < 4; ++ni)
      bfr[ni] = *(const bf16x8*)(Bs + (wn + ni * 16 + fr) * LDT + fq * 8);
#pragma unroll
    for (int mi = 0; mi < 4; ++mi)
#pragma unroll
      for (int ni = 0; ni < 4; ++ni)
        acc[mi][ni] = __builtin_amdgcn_mfma_f32_16x16x32_bf16(af[mi], bfr[ni], acc[mi][ni], 0, 0, 0);
  }

#pragma unroll
  for (int mi = 0; mi < 4; ++mi) {
#pragma unroll
    for (int ni = 0; ni < 4; ++ni) {
      const int col = n0 + wn + ni * 16 + fr;
      const float bv = bias[col];
#pragma unroll
      for (int rr = 0; rr < 4; ++rr) {
        const int row = m0 + wm + mi * 16 + fq * 4 + rr;   // C/D: row=quad*4+reg, col=lane&15
        float v = acc[mi][ni][rr] + bv;
        if (EPI == 1) {
          const float u = 0.7978845608028654f * (v + 0.044715f * v * v * v);
          v = 0.5f * v * (1.f + tanhf(u));                 // jax approximate gelu
          ((u16*)Cout)[(size_t)row * Nn + col] = f2bf(v);
        } else if (EPI == 2) {
          ((float*)Cout)[(size_t)row * Nn + col] = v + resid[(size_t)row * Nn + col];
        } else {
          ((float*)Cout)[(size_t)row * Nn + col] = v;
        }
      }
    }
  }
}

// ---------------------------------------------------------------- edge pass
// One wave per edge. lane: h=lane>>3 (head), j=lane&7 (8-dim chunk).
// No segment-max: logits bounded (~|8|), exp() safe in fp32; softmax is shift-invariant.
__global__ __launch_bounds__(256) void edge_kernel(
    const float* __restrict__ qk, const float* __restrict__ att_bias,
    const float* __restrict__ dist, const float* __restrict__ src_pos,
    const int* __restrict__ row_index, const int* __restrict__ src_index,
    const int* __restrict__ org_to_src,
    float* __restrict__ den, float* __restrict__ wsum, float* __restrict__ wsp)
{
  const int e = blockIdx.x * 4 + (threadIdx.x >> 6);
  const int lane = threadIdx.x & 63;
  const int h = lane >> 3, j = lane & 7;
  const int row = row_index[e];
  const int s = src_index[e];
  const int kr = org_to_src[s];
  const float* qp = qk + (size_t)row * 1024 + h * 64 + j * 8;
  const float* kp = qk + (size_t)kr * 1024 + 512 + h * 64 + j * 8;
  const float4 qa = *(const float4*)qp, qb = *(const float4*)(qp + 4);
  const float4 ka = *(const float4*)kp, kb = *(const float4*)(kp + 4);
  float p = qa.x * ka.x + qa.y * ka.y + qa.z * ka.z + qa.w * ka.w
          + qb.x * kb.x + qb.y * kb.y + qb.z * kb.z + qb.w * kb.w;
  p += __shfl_xor(p, 1, 64);
  p += __shfl_xor(p, 2, 64);
  p += __shfl_xor(p, 4, 64);                     // all 8 lanes of head group hold the dot
  const float logit = p * 0.125f + att_bias[(size_t)h * E_EDGES + e];
  const float pe = expf(logit);
  const float dv = dist[e];
  const float inv = (dv == 0.f) ? 0.f : 1.f / dv;
  const float w = pe * inv;
  const int idx = row * 8 + h;
  if (j == 0)      atomicAdd(&den[idx], pe);
  else if (j == 1) atomicAdd(&wsum[idx], w);
  else if (j < 5)  atomicAdd(&wsp[idx * 3 + (j - 2)], w * src_pos[(size_t)s * 3 + (j - 2)]);
}

// ---------------------------------------------------------------- feat assembly
__global__ __launch_bounds__(256) void feat_kernel(
    const float* __restrict__ den, const float* __restrict__ wsum,
    const float* __restrict__ wsp, const float* __restrict__ pos,
    u16* __restrict__ zcat)
{
  const int t = blockIdx.x * 256 + threadIdx.x;   // 0 .. N*H-1
  const int row = t >> 3, h = t & 7;
  const float d = den[t];
  const float invd = (d != 0.f) ? 1.f / d : 0.f;  // empty rows -> feat 0 (matches ref)
  const float rsum = wsum[t] * invd;
  u16* out = zcat + (size_t)row * KIN + D + h * 3;
#pragma unroll
  for (int c = 0; c < 3; ++c)
    out[c] = f2bf(wsp[t * 3 + c] * invd - rsum * pos[row * 3 + c]);
}

// ---------------------------------------------------------------- launch
extern "C" void kernel_launch(void* const* d_in, const int* in_sizes, int n_in,
                              void* d_out, int out_size, void* d_ws, size_t ws_size,
                              hipStream_t stream)
{
  const float* x        = (const float*)d_in[0];
  const float* Wq       = (const float*)d_in[1];
  const float* bq       = (const float*)d_in[2];
  const float* Wk       = (const float*)d_in[3];
  const float* bk       = (const float*)d_in[4];
  const float* g_att    = (const float*)d_in[5];
  const float* b_att    = (const float*)d_in[6];
  const float* g_mlp    = (const float*)d_in[7];
  const float* b_mlp    = (const float*)d_in[8];
  const float* W_in     = (const float*)d_in[9];
  const float* b_in     = (const float*)d_in[10];
  const float* W_out    = (const float*)d_in[11];
  const float* b_out    = (const float*)d_in[12];
  const float* att_bias = (const float*)d_in[13];
  const float* dist     = (const float*)d_in[14];
  const float* pos      = (const float*)d_in[15];
  const float* src_pos  = (const float*)d_in[16];
  const int* row_index  = (const int*)d_in[17];
  const int* src_index  = (const int*)d_in[18];
  const int* org_to_src = (const int*)d_in[19];

  char* ws = (char*)d_ws;
  u16*   zatt = (u16*)(ws + OFF_ZATT);
  u16*   zcat = (u16*)(ws + OFF_ZCAT);
  u16*   wqk  = (u16*)(ws + OFF_WQK);
  float* bqk  = (float*)(ws + OFF_BQK);
  u16*   win  = (u16*)(ws + OFF_WIN);
  u16*   wout = (u16*)(ws + OFF_WOUT);
  float* qk   = (float*)(ws + OFF_QK);
  float* den  = (float*)(ws + OFF_DEN);
  float* wsum = (float*)(ws + OFF_WSUM);
  float* wsp  = (float*)(ws + OFF_WSP);
  u16*   hbf  = (u16*)(ws + OFF_HBF);

  // den+wsum+wsp are contiguous: one async memset (ws is poisoned each call)
  hipMemsetAsync(ws + OFF_DEN, 0, 2621440, stream);

  prep_weights<<<2176, 256, 0, stream>>>(Wq, Wk, bq, bk, W_in, W_out, wqk, bqk, win, wout);
  ln_kernel<<<N_NODES, 256, 0, stream>>>(x, g_att, b_att, g_mlp, b_mlp, zatt, zcat);
  gemm_nt<0><<<dim3(8, 128), 256, 0, stream>>>(zatt, wqk, bqk, nullptr, qk, N_NODES, 1024, 512);
  edge_kernel<<<E_EDGES / 4, 256, 0, stream>>>(qk, att_bias, dist, src_pos,
                                               row_index, src_index, org_to_src, den, wsum, wsp);
  feat_kernel<<<512, 256, 0, stream>>>(den, wsum, wsp, pos, zcat);
  gemm_nt<1><<<dim3(8, 128), 256, 0, stream>>>(zcat, win, b_in, nullptr, hbf, N_NODES, 1024, KIN);
  gemm_nt<2><<<dim3(4, 128), 256, 0, stream>>>(hbf, wout, b_out, x, d_out, N_NODES, 512, 1024);
}

// Round 2
// 362.968 us; speedup vs baseline: 1.1721x; 1.1721x over previous
//
#include <hip/hip_runtime.h>
#include <math.h>

// PositionFeaturizer on MI355X — round 1:
//  * qk stored bf16 (halves edge-gather traffic: 1 GB -> 512 MB logical)
//  * edge_kernel: 2 edges/wave, 16 dims/lane (4 outstanding 16B loads/lane)
//  * GEMMs: global_load_lds width-16 staging (m97 structure, unpadded BK=32 LDS)

typedef unsigned short u16;
typedef __attribute__((ext_vector_type(8))) short bf16x8;   // 8 bf16 in 4 VGPRs
typedef __attribute__((ext_vector_type(4))) float f32x4;

constexpr int N_NODES = 16384;
constexpr int E_EDGES = 262144;
constexpr int D = 512;
constexpr int KIN = 544;    // 536 padded to multiple of 32

// workspace layout (bytes)
constexpr size_t OFF_ZATT = 0;                       // 16384*512*2  = 16,777,216
constexpr size_t OFF_ZCAT = 16777216;                // 16384*544*2  = 17,825,792
constexpr size_t OFF_WQK  = 34603008;                // 1024*512*2   = 1,048,576
constexpr size_t OFF_BQK  = 35651584;                // 1024*4       = 4,096
constexpr size_t OFF_WIN  = 35655680;                // 1024*544*2   = 1,114,112
constexpr size_t OFF_WOUT = 36769792;                // 512*1024*2   = 1,048,576
constexpr size_t OFF_QK   = 37818368;                // 16384*1024*2 = 33,554,432 (bf16 now)
constexpr size_t OFF_DEN  = 104927232;               // 16384*8*4    = 524,288
constexpr size_t OFF_WSUM = 105451520;               // 524,288
constexpr size_t OFF_WSP  = 105975808;               // 16384*8*3*4  = 1,572,864
constexpr size_t OFF_HBF  = 107548672;               // 16384*1024*2 = 33,554,432

static __device__ __forceinline__ u16 f2bf(float f) {
  union { float f; unsigned int u; } v; v.f = f;
  unsigned int u = v.u;
  u = u + 0x7FFFu + ((u >> 16) & 1u);   // RNE
  return (u16)(u >> 16);
}
static __device__ __forceinline__ float bflo(unsigned int u) {
  union { unsigned int u; float f; } v; v.u = u << 16; return v.f;
}
static __device__ __forceinline__ float bfhi(unsigned int u) {
  union { unsigned int u; float f; } v; v.u = u & 0xFFFF0000u; return v.f;
}
// async global->LDS, 16 B per lane; LDS dest = wave-uniform base + lane*16
static __device__ __forceinline__ void gload16(const u16* g, u16* l) {
  __builtin_amdgcn_global_load_lds(
      (const __attribute__((address_space(1))) unsigned int*)g,
      (__attribute__((address_space(3))) unsigned int*)l, 16, 0, 0);
}

// ---------------------------------------------------------------- weights cast
__global__ __launch_bounds__(256) void prep_weights(
    const float* __restrict__ Wq, const float* __restrict__ Wk,
    const float* __restrict__ bq, const float* __restrict__ bk,
    const float* __restrict__ W_in, const float* __restrict__ W_out,
    u16* __restrict__ wqk, float* __restrict__ bqk,
    u16* __restrict__ win, u16* __restrict__ wout)
{
  const int gid = blockIdx.x * 256 + threadIdx.x;
  if (gid < 512 * 1024) {
    wqk[gid]  = f2bf(gid < 512 * 512 ? Wq[gid] : Wk[gid - 512 * 512]);
    wout[gid] = f2bf(W_out[gid]);
  }
  if (gid < 1024 * 544) {
    const int r = gid / 544, c = gid - r * 544;
    win[gid] = f2bf(c < 536 ? W_in[r * 536 + c] : 0.f);
  }
  if (gid < 1024) bqk[gid] = gid < 512 ? bq[gid] : bk[gid - 512];
}

// ---------------------------------------------------------------- dual layernorm
__global__ __launch_bounds__(256) void ln_kernel(
    const float* __restrict__ x,
    const float* __restrict__ g1, const float* __restrict__ b1,
    const float* __restrict__ g2, const float* __restrict__ b2,
    u16* __restrict__ zatt, u16* __restrict__ zcat)
{
  const int row = blockIdx.x;
  const int t = threadIdx.x;
  const float2 v = *(const float2*)(x + (size_t)row * D + t * 2);
  float s = v.x + v.y;
  float s2 = v.x * v.x + v.y * v.y;
#pragma unroll
  for (int m = 1; m < 64; m <<= 1) {
    s  += __shfl_xor(s, m, 64);
    s2 += __shfl_xor(s2, m, 64);
  }
  __shared__ float red[8];
  const int wv = t >> 6;
  if ((t & 63) == 0) { red[wv] = s; red[4 + wv] = s2; }
  __syncthreads();
  s  = red[0] + red[1] + red[2] + red[3];
  s2 = red[4] + red[5] + red[6] + red[7];
  const float mu = s * (1.f / D);
  const float var = s2 * (1.f / D) - mu * mu;
  const float rs = rsqrtf(var + 1e-5f);
  const int c0 = t * 2;
  const float n0 = (v.x - mu) * rs, n1 = (v.y - mu) * rs;
  zatt[(size_t)row * D + c0]       = f2bf(n0 * g1[c0] + b1[c0]);
  zatt[(size_t)row * D + c0 + 1]   = f2bf(n1 * g1[c0 + 1] + b1[c0 + 1]);
  zcat[(size_t)row * KIN + c0]     = f2bf(n0 * g2[c0] + b2[c0]);
  zcat[(size_t)row * KIN + c0 + 1] = f2bf(n1 * g2[c0 + 1] + b2[c0 + 1]);
  if (t < 32) zcat[(size_t)row * KIN + D + t] = 0;   // feat slot + K-pad zeroed
}

// ---------------------------------------------------------------- NT GEMM (bf16 MFMA)
// C[M,Nn] = A[M,K] @ B[Nn,K]^T + bias.
// EPI: 1=gelu->bf16 out; 2=+resid f32 out; 3=plain bf16 out.
// Staging: global_load_lds width 16. LDS tile unpadded (BK=32 shorts = 64 B rows),
// lane-order contiguous as the instruction requires (wave-uniform base + lane*16).
template <int EPI>
__global__ __launch_bounds__(256) void gemm_nt(
    const u16* __restrict__ A, const u16* __restrict__ B,
    const float* __restrict__ bias, const float* __restrict__ resid,
    void* __restrict__ Cout, int M, int Nn, int K)
{
  constexpr int BM = 128, BN = 128, BK = 32;
  __shared__ __align__(16) u16 As[BM * BK];
  __shared__ __align__(16) u16 Bs[BN * BK];
  const int tid = threadIdx.x;
  const int lane = tid & 63;
  const int wave = tid >> 6;
  const int m0 = blockIdx.y * BM;
  const int n0 = blockIdx.x * BN;
  const int wm = (wave >> 1) * 64;
  const int wn = (wave & 1) * 64;
  const int fr = lane & 15;   // fragment m/n index
  const int fq = lane >> 4;   // quad -> k-group / row-group
  const int srow = lane >> 2;            // staging: 4 lanes per 64 B row
  const int skoff = (lane & 3) * 8;      // shorts within row

  f32x4 acc[4][4];
#pragma unroll
  for (int i = 0; i < 4; ++i)
#pragma unroll
    for (int j = 0; j < 4; ++j) acc[i][j] = 0.f;

  for (int k0 = 0; k0 < K; k0 += BK) {
    __syncthreads();
#pragma unroll
    for (int r = 0; r < 2; ++r) {
      const int rowbase = r * 64 + wave * 16;        // wave-uniform
      gload16(A + (size_t)(m0 + rowbase + srow) * K + k0 + skoff, As + rowbase * BK);
      gload16(B + (size_t)(n0 + rowbase + srow) * K + k0 + skoff, Bs + rowbase * BK);
    }
    __syncthreads();
    bf16x8 af[4], bfr[4];
#pragma unroll
    for (int mi = 0; mi < 4; ++mi)
      af[mi] = *(const bf16x8*)(As + (wm + mi * 16 + fr) * BK + fq * 8);
#pragma unroll
    for (int ni = 0; ni < 4; ++ni)
      bfr[ni] = *(const bf16x8*)(Bs + (wn + ni * 16 + fr) * BK + fq * 8);
#pragma unroll
    for (int mi = 0; mi < 4; ++mi)
#pragma unroll
      for (int ni = 0; ni < 4; ++ni)
        acc[mi][ni] = __builtin_amdgcn_mfma_f32_16x16x32_bf16(af[mi], bfr[ni], acc[mi][ni], 0, 0, 0);
  }

#pragma unroll
  for (int mi = 0; mi < 4; ++mi) {
#pragma unroll
    for (int ni = 0; ni < 4; ++ni) {
      const int col = n0 + wn + ni * 16 + fr;
      const float bv = bias[col];
#pragma unroll
      for (int rr = 0; rr < 4; ++rr) {
        const int row = m0 + wm + mi * 16 + fq * 4 + rr;   // C/D: row=quad*4+reg, col=lane&15
        float v = acc[mi][ni][rr] + bv;
        if (EPI == 1) {
          const float u = 0.7978845608028654f * (v + 0.044715f * v * v * v);
          v = 0.5f * v * (1.f + tanhf(u));                 // jax approximate gelu
          ((u16*)Cout)[(size_t)row * Nn + col] = f2bf(v);
        } else if (EPI == 2) {
          ((float*)Cout)[(size_t)row * Nn + col] = v + resid[(size_t)row * Nn + col];
        } else {
          ((u16*)Cout)[(size_t)row * Nn + col] = f2bf(v);
        }
      }
    }
  }
}

// ---------------------------------------------------------------- edge pass
// 2 edges per wave; 32 lanes per edge: h=sub>>2 (head), j=sub&3 (16-dim chunk).
// No segment-max: logits bounded (~|8|), exp safe in fp32; softmax shift-invariant.
__global__ __launch_bounds__(256) void edge_kernel(
    const u16* __restrict__ qk, const float* __restrict__ att_bias,
    const float* __restrict__ dist, const float* __restrict__ src_pos,
    const int* __restrict__ row_index, const int* __restrict__ src_index,
    const int* __restrict__ org_to_src,
    float* __restrict__ den, float* __restrict__ wsum, float* __restrict__ wsp)
{
  const int lane = threadIdx.x & 63;
  const int wave = threadIdx.x >> 6;
  const int e = blockIdx.x * 8 + wave * 2 + (lane >> 5);
  const int sub = lane & 31;
  const int h = sub >> 2, j = sub & 3;
  const int row = row_index[e];
  const int s = src_index[e];
  const int kr = org_to_src[s];
  const u16* qp = qk + (size_t)row * 1024 + h * 64 + j * 16;
  const u16* kp = qk + (size_t)kr * 1024 + 512 + h * 64 + j * 16;
  const uint4 qa = *(const uint4*)qp, qb = *(const uint4*)(qp + 8);
  const uint4 ka = *(const uint4*)kp, kb = *(const uint4*)(kp + 8);
  float p = 0.f;
  {
    const unsigned int* qu = (const unsigned int*)&qa;
    const unsigned int* ku = (const unsigned int*)&ka;
    const unsigned int* qv = (const unsigned int*)&qb;
    const unsigned int* kv = (const unsigned int*)&kb;
#pragma unroll
    for (int i = 0; i < 4; ++i) {
      p = fmaf(bflo(qu[i]), bflo(ku[i]), p);
      p = fmaf(bfhi(qu[i]), bfhi(ku[i]), p);
      p = fmaf(bflo(qv[i]), bflo(kv[i]), p);
      p = fmaf(bfhi(qv[i]), bfhi(kv[i]), p);
    }
  }
  p += __shfl_xor(p, 1, 64);
  p += __shfl_xor(p, 2, 64);                     // all 4 lanes of head group hold the dot
  const float logit = p * 0.125f + att_bias[(size_t)h * E_EDGES + e];
  const float pe = expf(logit);
  const float dv = dist[e];
  const float inv = (dv == 0.f) ? 0.f : 1.f / dv;
  const float w = pe * inv;
  const int idx = row * 8 + h;
  if (j == 0) {
    atomicAdd(&den[idx], pe);
  } else if (j == 1) {
    atomicAdd(&wsum[idx], w);
    atomicAdd(&wsp[idx * 3 + 2], w * src_pos[(size_t)s * 3 + 2]);
  } else {
    atomicAdd(&wsp[idx * 3 + (j - 2)], w * src_pos[(size_t)s * 3 + (j - 2)]);
  }
}

// ---------------------------------------------------------------- feat assembly
__global__ __launch_bounds__(256) void feat_kernel(
    const float* __restrict__ den, const float* __restrict__ wsum,
    const float* __restrict__ wsp, const float* __restrict__ pos,
    u16* __restrict__ zcat)
{
  const int t = blockIdx.x * 256 + threadIdx.x;   // 0 .. N*H-1
  const int row = t >> 3, h = t & 7;
  const float d = den[t];
  const float invd = (d != 0.f) ? 1.f / d : 0.f;  // empty rows -> feat 0 (matches ref)
  const float rsum = wsum[t] * invd;
  u16* out = zcat + (size_t)row * KIN + D + h * 3;
#pragma unroll
  for (int c = 0; c < 3; ++c)
    out[c] = f2bf(wsp[t * 3 + c] * invd - rsum * pos[row * 3 + c]);
}

// ---------------------------------------------------------------- launch
extern "C" void kernel_launch(void* const* d_in, const int* in_sizes, int n_in,
                              void* d_out, int out_size, void* d_ws, size_t ws_size,
                              hipStream_t stream)
{
  const float* x        = (const float*)d_in[0];
  const float* Wq       = (const float*)d_in[1];
  const float* bq       = (const float*)d_in[2];
  const float* Wk       = (const float*)d_in[3];
  const float* bk       = (const float*)d_in[4];
  const float* g_att    = (const float*)d_in[5];
  const float* b_att    = (const float*)d_in[6];
  const float* g_mlp    = (const float*)d_in[7];
  const float* b_mlp    = (const float*)d_in[8];
  const float* W_in     = (const float*)d_in[9];
  const float* b_in     = (const float*)d_in[10];
  const float* W_out    = (const float*)d_in[11];
  const float* b_out    = (const float*)d_in[12];
  const float* att_bias = (const float*)d_in[13];
  const float* dist     = (const float*)d_in[14];
  const float* pos      = (const float*)d_in[15];
  const float* src_pos  = (const float*)d_in[16];
  const int* row_index  = (const int*)d_in[17];
  const int* src_index  = (const int*)d_in[18];
  const int* org_to_src = (const int*)d_in[19];

  char* ws = (char*)d_ws;
  u16*   zatt = (u16*)(ws + OFF_ZATT);
  u16*   zcat = (u16*)(ws + OFF_ZCAT);
  u16*   wqk  = (u16*)(ws + OFF_WQK);
  float* bqk  = (float*)(ws + OFF_BQK);
  u16*   win  = (u16*)(ws + OFF_WIN);
  u16*   wout = (u16*)(ws + OFF_WOUT);
  u16*   qk   = (u16*)(ws + OFF_QK);
  float* den  = (float*)(ws + OFF_DEN);
  float* wsum = (float*)(ws + OFF_WSUM);
  float* wsp  = (float*)(ws + OFF_WSP);
  u16*   hbf  = (u16*)(ws + OFF_HBF);

  // den+wsum+wsp are contiguous: one async memset (ws is poisoned each call)
  hipMemsetAsync(ws + OFF_DEN, 0, 2621440, stream);

  prep_weights<<<2176, 256, 0, stream>>>(Wq, Wk, bq, bk, W_in, W_out, wqk, bqk, win, wout);
  ln_kernel<<<N_NODES, 256, 0, stream>>>(x, g_att, b_att, g_mlp, b_mlp, zatt, zcat);
  gemm_nt<3><<<dim3(8, 128), 256, 0, stream>>>(zatt, wqk, bqk, nullptr, qk, N_NODES, 1024, 512);
  edge_kernel<<<E_EDGES / 8, 256, 0, stream>>>(qk, att_bias, dist, src_pos,
                                               row_index, src_index, org_to_src, den, wsum, wsp);
  feat_kernel<<<512, 256, 0, stream>>>(den, wsum, wsp, pos, zcat);
  gemm_nt<1><<<dim3(8, 128), 256, 0, stream>>>(zcat, win, b_in, nullptr, hbf, N_NODES, 1024, KIN);
  gemm_nt<2><<<dim3(4, 128), 256, 0, stream>>>(hbf, wout, b_out, x, d_out, N_NODES, 512, 1024);
}